// Round 11
// baseline (412.456 us; speedup 1.0000x reference)
//
#include <hip/hip_runtime.h>
#include <hip/hip_bf16.h>

#define B_ 4
#define D_ 64
#define N_ 16
#define HW_ 4096

#define LDSA 72
#define LDSB 66
#define GST 68   // fp32 g-plane LDS row stride (mult of 4 -> 16B aligned v4f)

// workspace offsets (bytes)
#define OFF_D2    0u
#define OFF_ATAB  8192u
#define OFF_W9    16384u
#define OFF_UNT   131072u
#define OFF_DELTA 2228224u
#define OFF_BVAL  6422528u
#define OFF_CVAL  7471104u
#define OFF_PART  8519680u

typedef __bf16 v8bf __attribute__((ext_vector_type(8)));
typedef float  v4f  __attribute__((ext_vector_type(4)));

__device__ __forceinline__ unsigned short f2bf(float f){
  __hip_bfloat16 h = __float2bfloat16(f);
  return *reinterpret_cast<unsigned short*>(&h);
}
__device__ __forceinline__ v8bf ld8bf(const unsigned short* p){
  union{uint4 u; v8bf v;} c; c.u = *(const uint4*)p; return c.v;
}

// ------- prep: D2 table + Atab + weight repack + GN partials (merged) -------
__global__ void k_prep(const float* __restrict__ logA,
                       const float* __restrict__ wd,
                       const float* __restrict__ wB,
                       const float* __restrict__ wC,
                       const float* __restrict__ u,
                       unsigned short* __restrict__ D2w,
                       float* __restrict__ Atab,
                       unsigned short* __restrict__ W9,
                       float* __restrict__ part){
  __shared__ float ls[4], ls2[4];
  int blk = blockIdx.x;
  int t = threadIdx.x;
  if(blk < 20){
    int g = blk*256 + t;
    if(g < 4096){
      int r = g>>6, m = g&63;
      int p = (r - m) & 63;
      float s = 0.f;
      for(int k=1;k<32;k++) s += (float)k * sinf(0.09817477042468103f * (float)(k*p));
      D2w[g] = f2bf(-0.0030679615757712823f * s);
    } else if(g < 5120){
      int idx = g - 4096;
      Atab[idx] = -__expf(logA[idx]);
    }
  } else if(blk < 44){
    int idx = (blk-20)*256 + t;   // 0..6143
    if(idx >= 96*64) return;
    int co = idx>>6, ci = idx&63;
    const float* src;
    if(co < 64)      src = wd + ((size_t)co*64 + ci)*9;
    else if(co < 80) src = wB + ((size_t)(co-64)*64 + ci)*9;
    else             src = wC + ((size_t)(co-80)*64 + ci)*9;
    for(int tap=0; tap<9; tap++)
      W9[((size_t)tap*96 + co)*64 + ci] = f2bf(src[tap]);
  } else {
    int bid = blk - 44;                      // 0..1023 : bg*64 + sub
    const float* base = u + (size_t)(bid>>6)*65536 + (size_t)(bid&63)*1024;
    float4 v = ((const float4*)base)[t];
    float s  = v.x+v.y+v.z+v.w;
    float s2 = v.x*v.x+v.y*v.y+v.z*v.z+v.w*v.w;
    #pragma unroll
    for(int o=32;o>0;o>>=1){ s += __shfl_down(s,o); s2 += __shfl_down(s2,o); }
    int wv = t>>6;
    if((t&63)==0){ ls[wv]=s; ls2[wv]=s2; }
    __syncthreads();
    if(t==0){
      part[bid]        = ls[0]+ls[1]+ls[2]+ls[3];
      part[1024 + bid] = ls2[0]+ls2[1]+ls2[2]+ls2[3];
    }
  }
}

// ---------------- GN finalize (folded) + apply + transpose ------------------
__global__ __launch_bounds__(512) void k_unT(
    const float* __restrict__ u_t,
    const float* __restrict__ part,
    const float* __restrict__ gamma, const float* __restrict__ beta,
    unsigned short* __restrict__ unT){
  __shared__ unsigned short T[64*LDSA];
  __shared__ float smean[16], srstd[16];
  int bid = blockIdx.x;
  int b = bid>>6, h = bid&63;
  int t = threadIdx.x;                 // 0..511
  if(t < 256){
    int g = t>>4, i = t&15;
    float S=0.f, S2=0.f;
    #pragma unroll
    for(int j=0;j<4;j++){
      S  += part[g*64 + i*4 + j];
      S2 += part[1024 + g*64 + i*4 + j];
    }
    #pragma unroll
    for(int o=8;o>0;o>>=1){ S += __shfl_down(S,o,16); S2 += __shfl_down(S2,o,16); }
    if(i==0){
      float mu = S/65536.f;
      float var = S2/65536.f - mu*mu;
      smean[g]=mu; srstd[g]=rsqrtf(var+1e-5f);
    }
  }
  __syncthreads();
  int w = t&63, cg = t>>6;             // cg = wave 0..7
  #pragma unroll
  for(int i=0;i<8;i++){
    int c = cg*8 + i;
    float x = u_t[(((size_t)b*64 + c)*64 + h)*64 + w];
    int g = c>>4;
    float v = (x - smean[b*4+g])*srstd[b*4+g]*gamma[c] + beta[c];
    T[w*LDSA + c] = f2bf(v);
  }
  __syncthreads();
  int w2 = t>>3, cq = t&7;             // 64 pixels x 8 ci-octets
  uint4 v0 = *(uint4*)&T[w2*LDSA + cq*8];
  uint4* dst = (uint4*)(unT + ((size_t)b*HW_ + h*64 + w2)*64 + cq*8);
  dst[0] = v0;
}

// ---------------- conv as 9 shifted GEMMs via MFMA (6-way co split) ---------
__global__ __launch_bounds__(256) void k_conv(
    const unsigned short* __restrict__ unT,
    const unsigned short* __restrict__ W9,
    const float* __restrict__ b_d,
    const float* __restrict__ dtp,
    float* __restrict__ deltaw, float* __restrict__ Bvalw, float* __restrict__ Cvalw){
  int bid = blockIdx.x;
  int cg = bid >> 8;                   // 0..5  (co group of 16)
  int b = (bid>>6) & 3, h = bid & 63;
  int t = threadIdx.x;
  int wv = t>>6, l = t&63;
  int lr = l&15, lk = l>>4;
  v4f acc = (v4f){0.f,0.f,0.f,0.f};
  int wpix = wv*16 + lr;
  #pragma unroll
  for(int tap=0; tap<9; tap++){
    int dy = tap/3 - 1, dx = tap - (tap/3)*3 - 1;
    int hh = (h+dy)&63;
    int ww = (wpix+dx)&63;
    const unsigned short* bp = unT + ((size_t)b*HW_ + hh*64 + ww)*64;
    const unsigned short* ap = W9 + ((size_t)tap*96 + cg*16)*64;
    #pragma unroll
    for(int ks=0; ks<2; ks++){
      int k0 = ks*32 + lk*8;
      v8bf bfrag = ld8bf(bp + k0);
      v8bf afrag = ld8bf(ap + lr*64 + k0);
      acc = __builtin_amdgcn_mfma_f32_16x16x32_bf16(afrag, bfrag, acc, 0,0,0);
    }
  }
  float dt = dtp[0];
  int p = h*64 + wpix;
  #pragma unroll
  for(int r=0;r<4;r++){
    int co = cg*16 + lk*4 + r;
    float v = acc[r];
    if(cg < 4){
      float x = v + b_d[co] + dt;
      float sp = (x > 15.f) ? x : log1pf(__expf(x));
      sp = fminf(fmaxf(sp, 1e-4f), 5.f);
      deltaw[((size_t)b*64 + co)*HW_ + p] = sp;
    } else if(cg == 4){
      Bvalw[((size_t)b*16 + (co-64))*HW_ + p] = v;
    } else {
      Cvalw[((size_t)b*16 + (co-80))*HW_ + p] = v;
    }
  }
}

// ------- full state update: one (b,d,n) plane per block ---------------------
// grad (MFMA) + m0/mx/my updates in one block. m0 is read from HBM once
// (phase 1); the tail re-reads it via L1/L2 (same block, just-touched lines).
// u/B planes are L2-hot (shared by 16/64 sibling blocks via XCD swizzle).
// y is deferred to k_y (reads m0_new from L3). No atomics, 2 barriers.
__global__ __launch_bounds__(256) void k_state(
    const float* __restrict__ u_t,
    const float* __restrict__ s_prev,
    const unsigned short* __restrict__ D2w,
    const float* __restrict__ Atab,
    const float* __restrict__ deltaw,
    const float* __restrict__ Bvalw,
    float* __restrict__ out_s){
  __shared__ __align__(16) char sm[17664];
  unsigned short* Ms72 = (unsigned short*)sm;            // staging: 9216 B
  unsigned short* MsT  = (unsigned short*)(sm + 9216);   // staging: 8448 B
  float* gL = (float*)sm;                                // g plane: 17408 B

  const size_t PL = (size_t)D_*N_*HW_;
  int bid = blockIdx.x;                                  // 4096 % 8 == 0
  int lid = (bid & 7)*512 + (bid >> 3);                  // bijective XCD swizzle
  int n  = lid & 15;
  int d  = (lid>>4) & 63;
  int b  = lid >> 10;
  int t = threadIdx.x;
  int wv = t>>6, l = t&63;
  int lr = l & 15, lk = l >> 4;
  int r0 = wv*16;

  size_t bd = (size_t)b*64 + d;
  size_t off = (size_t)b*3*PL + (size_t)d*(N_*HW_) + (size_t)n*HW_;
  const float* m0p = s_prev + off;
  const float* mxp = m0p + PL;
  const float* myp = m0p + 2*PL;
  float* so = out_s + off;
  const float* dp = deltaw + bd*HW_;
  const float* up = u_t + bd*HW_;
  const float* Bp = Bvalw + ((size_t)b*16 + n)*HW_;

  // ---- phase 1: m0 -> bf16 LDS staging (row-major + transposed) ----
  #pragma unroll
  for(int j=0;j<4;j++){
    int chunk = t + 256*j;             // 0..1023 float4 chunks
    int rrow = chunk>>4, cb = chunk&15;
    v4f v = ((const v4f*)m0p)[chunk];
    unsigned short e0=f2bf(v[0]), e1=f2bf(v[1]), e2=f2bf(v[2]), e3=f2bf(v[3]);
    unsigned int lo = (unsigned int)e0 | ((unsigned int)e1<<16);
    unsigned int hi = (unsigned int)e2 | ((unsigned int)e3<<16);
    unsigned int* d72 = (unsigned int*)&Ms72[rrow*LDSA + cb*4];
    d72[0]=lo; d72[1]=hi;
    int c0 = cb*4;
    MsT[(c0  )*LDSB + rrow] = e0;
    MsT[(c0+1)*LDSB + rrow] = e1;
    MsT[(c0+2)*LDSB + rrow] = e2;
    MsT[(c0+3)*LDSB + rrow] = e3;
  }
  __syncthreads();

  // ---- phase 2: spectral-gradient MFMAs ----
  v4f gxs[4], gys[4];
  #pragma unroll
  for(int ct=0; ct<4; ct++){
    v4f gx = {0.f,0.f,0.f,0.f}, gy = {0.f,0.f,0.f,0.f};
    #pragma unroll
    for(int ks=0; ks<2; ks++){
      int k0 = ks*32 + lk*8;
      // grad_x = M * D2^T : A = M rows (LDS), B[k][j]=D2[j][k] (global/L2)
      v8bf a_gx = ld8bf(&Ms72[(r0+lr)*LDSA + k0]);
      v8bf b_gx = ld8bf(D2w + (ct*16+lr)*64 + k0);
      gx = __builtin_amdgcn_mfma_f32_16x16x32_bf16(a_gx, b_gx, gx, 0,0,0);
      // grad_y = D2 * M : A = D2 rows (global/L2), B[k][j]=M[k][j]=MsT[j][k]
      v8bf a_gy = ld8bf(D2w + (r0+lr)*64 + k0);
      v8bf b_gy = ld8bf(&MsT[(ct*16+lr)*LDSB + k0]);
      gy = __builtin_amdgcn_mfma_f32_16x16x32_bf16(a_gy, b_gy, gy, 0,0,0);
    }
    gxs[ct] = gx; gys[ct] = gy;
  }
  __syncthreads();   // all MFMA LDS reads done before overwriting with g

  float An = Atab[d*16 + n];

  // ---- tail (barrier-free, per-wave stripe) ----
  // pass 1: scatter gx; m0_new + mx_new updates
  #pragma unroll
  for(int ct=0; ct<4; ct++){
    #pragma unroll
    for(int r=0;r<4;r++)
      gL[(r0 + lk*4 + r)*GST + ct*16 + lr] = gxs[ct][r];
  }
  v4f ab[4];
  #pragma unroll
  for(int j=0;j<4;j++){
    int q = r0*16 + j*64 + l;          // own-wave rows
    int row = q>>4, c4 = (q&15)<<2;
    v4f dv = ((const v4f*)dp)[q];
    #pragma unroll
    for(int r=0;r<4;r++) ab[j][r] = __expf(dv[r]*An);
    v4f m0 = ((const v4f*)m0p)[q];     // L1/L2 hit: read in phase 1
    v4f uv = ((const v4f*)up)[q];      // L2-hot (shared by 16 n-blocks)
    v4f Bv = ((const v4f*)Bp)[q];      // L2-hot (shared by 64 d-blocks)
    ((v4f*)so)[q] = ab[j]*m0 + dv*Bv*uv;
    v4f gx = *(const v4f*)&gL[row*GST + c4];
    v4f mx = ((const v4f*)mxp)[q];
    ((v4f*)(so + PL))[q] = ab[j]*(mx - gx);
  }
  // pass 2: scatter gy; my_new update
  #pragma unroll
  for(int ct=0; ct<4; ct++){
    #pragma unroll
    for(int r=0;r<4;r++)
      gL[(r0 + lk*4 + r)*GST + ct*16 + lr] = gys[ct][r];
  }
  #pragma unroll
  for(int j=0;j<4;j++){
    int q = r0*16 + j*64 + l;
    int row = q>>4, c4 = (q&15)<<2;
    v4f gy = *(const v4f*)&gL[row*GST + c4];
    v4f my = ((const v4f*)myp)[q];
    ((v4f*)(so + 2*PL))[q] = ab[j]*(my - gy);
  }
}

// ---------------- y epilogue: y = sum_n m0_new*C + u*D_param ----------------
// m0_new was written moments ago -> L3-resident (67MB < 256MB L3).
__global__ __launch_bounds__(256) void k_y(
    const float* __restrict__ m0new,    // = out_s base
    const float* __restrict__ Cvalw,
    const float* __restrict__ u_t,
    const float* __restrict__ Dp,
    float* __restrict__ out_y){
  int i = blockIdx.x*256 + threadIdx.x;   // 0..262143 float4s
  int b = i>>16;
  int d = (i>>10)&63;
  int pq = i & 1023;
  const size_t PL = (size_t)D_*N_*HW_;
  float Dv = Dp[d];
  const float4* m0b = (const float4*)(m0new + (size_t)b*3*PL + (size_t)d*(N_*HW_)) + pq;
  const float4* Cb  = (const float4*)Cvalw + (size_t)b*16*1024 + pq;
  float4 acc = {0.f,0.f,0.f,0.f};
  #pragma unroll
  for(int n=0;n<16;n++){
    float4 m = m0b[(size_t)n*1024];
    float4 c = Cb[(size_t)n*1024];
    acc.x += m.x*c.x; acc.y += m.y*c.y; acc.z += m.z*c.z; acc.w += m.w*c.w;
  }
  float4 uv = ((const float4*)u_t)[i];
  float4 o;
  o.x = acc.x + uv.x*Dv;
  o.y = acc.y + uv.y*Dv;
  o.z = acc.z + uv.z*Dv;
  o.w = acc.w + uv.w*Dv;
  ((float4*)out_y)[i] = o;
}

extern "C" void kernel_launch(void* const* d_in, const int* in_sizes, int n_in,
                              void* d_out, int out_size, void* d_ws, size_t ws_size,
                              hipStream_t stream){
  const float* u_t    = (const float*)d_in[0];
  const float* s_prev = (const float*)d_in[1];
  const float* gamma  = (const float*)d_in[2];
  const float* beta   = (const float*)d_in[3];
  const float* w_d    = (const float*)d_in[4];
  const float* b_d    = (const float*)d_in[5];
  const float* w_B    = (const float*)d_in[6];
  const float* w_C    = (const float*)d_in[7];
  const float* logA   = (const float*)d_in[8];
  const float* Dp     = (const float*)d_in[9];
  const float* dtp    = (const float*)d_in[10];

  char* ws = (char*)d_ws;
  unsigned short* D2w  = (unsigned short*)(ws + OFF_D2);
  float* Atab          = (float*)(ws + OFF_ATAB);
  unsigned short* W9   = (unsigned short*)(ws + OFF_W9);
  unsigned short* unT  = (unsigned short*)(ws + OFF_UNT);
  float* deltaw        = (float*)(ws + OFF_DELTA);
  float* Bvalw         = (float*)(ws + OFF_BVAL);
  float* Cvalw         = (float*)(ws + OFF_CVAL);
  float* part          = (float*)(ws + OFF_PART);

  float* out_y = (float*)d_out;
  float* out_s = out_y + 1048576;

  k_prep  <<<1068, 256, 0, stream>>>(logA, w_d, w_B, w_C, u_t, D2w, Atab, W9, part);
  k_unT   <<<256, 512, 0, stream>>>(u_t, part, gamma, beta, unT);
  k_conv  <<<1536, 256, 0, stream>>>(unT, W9, b_d, dtp, deltaw, Bvalw, Cvalw);
  k_state <<<4096, 256, 0, stream>>>(u_t, s_prev, D2w, Atab, deltaw, Bvalw, out_s);
  k_y     <<<1024, 256, 0, stream>>>(out_s, Cvalw, u_t, Dp, out_y);
}

// Round 12
// 399.104 us; speedup vs baseline: 1.0335x; 1.0335x over previous
//
#include <hip/hip_runtime.h>
#include <hip/hip_bf16.h>

#define B_ 4
#define D_ 64
#define N_ 16
#define HW_ 4096

#define LDSA 72
#define LDSB 66
#define GST 68   // fp32 g-plane LDS row stride (mult of 4 -> 16B aligned v4f)

// workspace offsets (bytes)
#define OFF_D2    0u
#define OFF_ATAB  8192u
#define OFF_W9    16384u
#define OFF_UNT   131072u
#define OFF_DELTA 2228224u
#define OFF_BVAL  6422528u
#define OFF_CVAL  7471104u
#define OFF_PART  8519680u

typedef __bf16 v8bf __attribute__((ext_vector_type(8)));
typedef float  v4f  __attribute__((ext_vector_type(4)));

__device__ __forceinline__ unsigned short f2bf(float f){
  __hip_bfloat16 h = __float2bfloat16(f);
  return *reinterpret_cast<unsigned short*>(&h);
}
__device__ __forceinline__ v8bf ld8bf(const unsigned short* p){
  union{uint4 u; v8bf v;} c; c.u = *(const uint4*)p; return c.v;
}

// ------- prep: D2 table + Atab + weight repack + GN partials (merged) -------
__global__ void k_prep(const float* __restrict__ logA,
                       const float* __restrict__ wd,
                       const float* __restrict__ wB,
                       const float* __restrict__ wC,
                       const float* __restrict__ u,
                       unsigned short* __restrict__ D2w,
                       float* __restrict__ Atab,
                       unsigned short* __restrict__ W9,
                       float* __restrict__ part){
  __shared__ float ls[4], ls2[4];
  int blk = blockIdx.x;
  int t = threadIdx.x;
  if(blk < 20){
    int g = blk*256 + t;
    if(g < 4096){
      int r = g>>6, m = g&63;
      int p = (r - m) & 63;
      float s = 0.f;
      for(int k=1;k<32;k++) s += (float)k * sinf(0.09817477042468103f * (float)(k*p));
      D2w[g] = f2bf(-0.0030679615757712823f * s);
    } else if(g < 5120){
      int idx = g - 4096;
      Atab[idx] = -__expf(logA[idx]);
    }
  } else if(blk < 44){
    int idx = (blk-20)*256 + t;   // 0..6143
    if(idx >= 96*64) return;
    int co = idx>>6, ci = idx&63;
    const float* src;
    if(co < 64)      src = wd + ((size_t)co*64 + ci)*9;
    else if(co < 80) src = wB + ((size_t)(co-64)*64 + ci)*9;
    else             src = wC + ((size_t)(co-80)*64 + ci)*9;
    for(int tap=0; tap<9; tap++)
      W9[((size_t)tap*96 + co)*64 + ci] = f2bf(src[tap]);
  } else {
    int bid = blk - 44;                      // 0..1023 : bg*64 + sub
    const float* base = u + (size_t)(bid>>6)*65536 + (size_t)(bid&63)*1024;
    float4 v = ((const float4*)base)[t];
    float s  = v.x+v.y+v.z+v.w;
    float s2 = v.x*v.x+v.y*v.y+v.z*v.z+v.w*v.w;
    #pragma unroll
    for(int o=32;o>0;o>>=1){ s += __shfl_down(s,o); s2 += __shfl_down(s2,o); }
    int wv = t>>6;
    if((t&63)==0){ ls[wv]=s; ls2[wv]=s2; }
    __syncthreads();
    if(t==0){
      part[bid]        = ls[0]+ls[1]+ls[2]+ls[3];
      part[1024 + bid] = ls2[0]+ls2[1]+ls2[2]+ls2[3];
    }
  }
}

// ---------------- GN finalize (folded) + apply + transpose ------------------
__global__ __launch_bounds__(512) void k_unT(
    const float* __restrict__ u_t,
    const float* __restrict__ part,
    const float* __restrict__ gamma, const float* __restrict__ beta,
    unsigned short* __restrict__ unT){
  __shared__ unsigned short T[64*LDSA];
  __shared__ float smean[16], srstd[16];
  int bid = blockIdx.x;
  int b = bid>>6, h = bid&63;
  int t = threadIdx.x;                 // 0..511
  if(t < 256){
    int g = t>>4, i = t&15;
    float S=0.f, S2=0.f;
    #pragma unroll
    for(int j=0;j<4;j++){
      S  += part[g*64 + i*4 + j];
      S2 += part[1024 + g*64 + i*4 + j];
    }
    #pragma unroll
    for(int o=8;o>0;o>>=1){ S += __shfl_down(S,o,16); S2 += __shfl_down(S2,o,16); }
    if(i==0){
      float mu = S/65536.f;
      float var = S2/65536.f - mu*mu;
      smean[g]=mu; srstd[g]=rsqrtf(var+1e-5f);
    }
  }
  __syncthreads();
  int w = t&63, cg = t>>6;             // cg = wave 0..7
  #pragma unroll
  for(int i=0;i<8;i++){
    int c = cg*8 + i;
    float x = u_t[(((size_t)b*64 + c)*64 + h)*64 + w];
    int g = c>>4;
    float v = (x - smean[b*4+g])*srstd[b*4+g]*gamma[c] + beta[c];
    T[w*LDSA + c] = f2bf(v);
  }
  __syncthreads();
  int w2 = t>>3, cq = t&7;             // 64 pixels x 8 ci-octets
  uint4 v0 = *(uint4*)&T[w2*LDSA + cq*8];
  uint4* dst = (uint4*)(unT + ((size_t)b*HW_ + h*64 + w2)*64 + cq*8);
  dst[0] = v0;
}

// ---------------- conv as 9 shifted GEMMs via MFMA (6-way co split) ---------
__global__ __launch_bounds__(256) void k_conv(
    const unsigned short* __restrict__ unT,
    const unsigned short* __restrict__ W9,
    const float* __restrict__ b_d,
    const float* __restrict__ dtp,
    float* __restrict__ deltaw, float* __restrict__ Bvalw, float* __restrict__ Cvalw){
  int bid = blockIdx.x;
  int cg = bid >> 8;                   // 0..5  (co group of 16)
  int b = (bid>>6) & 3, h = bid & 63;
  int t = threadIdx.x;
  int wv = t>>6, l = t&63;
  int lr = l&15, lk = l>>4;
  v4f acc = (v4f){0.f,0.f,0.f,0.f};
  int wpix = wv*16 + lr;
  #pragma unroll
  for(int tap=0; tap<9; tap++){
    int dy = tap/3 - 1, dx = tap - (tap/3)*3 - 1;
    int hh = (h+dy)&63;
    int ww = (wpix+dx)&63;
    const unsigned short* bp = unT + ((size_t)b*HW_ + hh*64 + ww)*64;
    const unsigned short* ap = W9 + ((size_t)tap*96 + cg*16)*64;
    #pragma unroll
    for(int ks=0; ks<2; ks++){
      int k0 = ks*32 + lk*8;
      v8bf bfrag = ld8bf(bp + k0);
      v8bf afrag = ld8bf(ap + lr*64 + k0);
      acc = __builtin_amdgcn_mfma_f32_16x16x32_bf16(afrag, bfrag, acc, 0,0,0);
    }
  }
  float dt = dtp[0];
  int p = h*64 + wpix;
  #pragma unroll
  for(int r=0;r<4;r++){
    int co = cg*16 + lk*4 + r;
    float v = acc[r];
    if(cg < 4){
      float x = v + b_d[co] + dt;
      float sp = (x > 15.f) ? x : log1pf(__expf(x));
      sp = fminf(fmaxf(sp, 1e-4f), 5.f);
      deltaw[((size_t)b*64 + co)*HW_ + p] = sp;
    } else if(cg == 4){
      Bvalw[((size_t)b*16 + (co-64))*HW_ + p] = v;
    } else {
      Cvalw[((size_t)b*16 + (co-80))*HW_ + p] = v;
    }
  }
}

// ------- merged state kernel, INTERLEAVED paths -----------------------------
// Every 5th GROUP-OF-8 consecutive blocks runs the streaming update path
// (128 groups = 1024 blocks); the rest run the grad path (4096 blocks).
// Group-of-8 granularity keeps bid&7 == XCD, so both bijective XCD swizzles
// stay valid, and each CU holds a ~1.6:6.4 mix of streaming and MFMA blocks
// for the WHOLE kernel (r10 drained its update blocks early). The two paths
// write disjoint out_s regions -> no ordering constraint.
__global__ __launch_bounds__(256) void k_state(
    const float* __restrict__ u_t,
    const float* __restrict__ s_prev,
    const unsigned short* __restrict__ D2w,
    const float* __restrict__ Atab,
    const float* __restrict__ deltaw,
    const float* __restrict__ Bvalw,
    const float* __restrict__ Cvalw,
    const float* __restrict__ Dp,
    float* __restrict__ out_y,
    float* __restrict__ out_s){
  __shared__ __align__(16) char sm[17664];
  const size_t PL = (size_t)D_*N_*HW_;
  int bid0 = blockIdx.x;
  int grp = bid0 >> 3, sub = bid0 & 7;   // sub == XCD
  int t = threadIdx.x;

  if(grp % 5 == 0){
    // ---------------- update path: m0_new + fused y, pure streaming --------
    int bid = sub*128 + grp/5;           // bijective XCD swizzle over 1024
    int ch = bid & 3;
    int d  = (bid>>2) & 63;
    int b  = bid >> 8;
    int q = ch*256 + t;                  // float4 index in a 4096-px plane

    size_t bd = (size_t)b*64 + d;
    size_t sb = (size_t)b*3*PL + (size_t)d*(N_*HW_);

    v4f dv = ((const v4f*)(deltaw + bd*HW_))[q];
    v4f uv = ((const v4f*)(u_t    + bd*HW_))[q];
    v4f yacc = {0.f,0.f,0.f,0.f};

    #pragma unroll 4
    for(int n=0; n<16; n++){
      size_t off = sb + (size_t)n*HW_;
      v4f m0 = ((const v4f*)(s_prev + off))[q];
      v4f Bv = ((const v4f*)(Bvalw + ((size_t)b*16+n)*HW_))[q];
      v4f Cv = ((const v4f*)(Cvalw + ((size_t)b*16+n)*HW_))[q];
      float An = Atab[d*16 + n];
      v4f ab;
      #pragma unroll
      for(int r=0;r<4;r++) ab[r] = __expf(dv[r]*An);
      v4f m0n = ab*m0 + dv*Bv*uv;
      ((v4f*)(out_s + off))[q] = m0n;
      yacc += m0n*Cv;
    }
    float Dv = Dp[d];
    v4f o = yacc + uv*Dv;
    ((v4f*)(out_y + bd*HW_))[q] = o;
    return;
  }

  // ---------------- grad path: gx/gy MFMA + mx/my update ----------------
  unsigned short* Ms72 = (unsigned short*)sm;            // staging: 9216 B
  unsigned short* MsT  = (unsigned short*)(sm + 9216);   // staging: 8448 B
  float* gL = (float*)sm;                                // g plane: 17408 B

  int lid = sub*512 + (grp - grp/5 - 1); // bijective XCD swizzle over 4096
  int n  = lid & 15;
  int d  = (lid>>4) & 63;
  int b  = lid >> 10;
  int wv = t>>6, l = t&63;
  int lr = l & 15, lk = l >> 4;
  int r0 = wv*16;

  size_t bd = (size_t)b*64 + d;
  size_t off = (size_t)b*3*PL + (size_t)d*(N_*HW_) + (size_t)n*HW_;
  const float* m0p = s_prev + off;
  const float* mxp = m0p + PL;
  const float* myp = m0p + 2*PL;
  float* so = out_s + off;
  const float* dp = deltaw + bd*HW_;

  // ---- phase 1: m0 -> bf16 LDS staging (row-major + transposed) ----
  #pragma unroll
  for(int j=0;j<4;j++){
    int chunk = t + 256*j;             // 0..1023 float4 chunks
    int rrow = chunk>>4, cb = chunk&15;
    v4f v = ((const v4f*)m0p)[chunk];
    unsigned short e0=f2bf(v[0]), e1=f2bf(v[1]), e2=f2bf(v[2]), e3=f2bf(v[3]);
    unsigned int lo = (unsigned int)e0 | ((unsigned int)e1<<16);
    unsigned int hi = (unsigned int)e2 | ((unsigned int)e3<<16);
    unsigned int* d72 = (unsigned int*)&Ms72[rrow*LDSA + cb*4];
    d72[0]=lo; d72[1]=hi;
    int c0 = cb*4;
    MsT[(c0  )*LDSB + rrow] = e0;
    MsT[(c0+1)*LDSB + rrow] = e1;
    MsT[(c0+2)*LDSB + rrow] = e2;
    MsT[(c0+3)*LDSB + rrow] = e3;
  }
  __syncthreads();

  // ---- phase 2: spectral-gradient MFMAs ----
  v4f gxs[4], gys[4];
  #pragma unroll
  for(int ct=0; ct<4; ct++){
    v4f gx = {0.f,0.f,0.f,0.f}, gy = {0.f,0.f,0.f,0.f};
    #pragma unroll
    for(int ks=0; ks<2; ks++){
      int k0 = ks*32 + lk*8;
      // grad_x = M * D2^T : A = M rows (LDS), B[k][j]=D2[j][k] (global/L2)
      v8bf a_gx = ld8bf(&Ms72[(r0+lr)*LDSA + k0]);
      v8bf b_gx = ld8bf(D2w + (ct*16+lr)*64 + k0);
      gx = __builtin_amdgcn_mfma_f32_16x16x32_bf16(a_gx, b_gx, gx, 0,0,0);
      // grad_y = D2 * M : A = D2 rows (global/L2), B[k][j]=M[k][j]=MsT[j][k]
      v8bf a_gy = ld8bf(D2w + (r0+lr)*64 + k0);
      v8bf b_gy = ld8bf(&MsT[(ct*16+lr)*LDSB + k0]);
      gy = __builtin_amdgcn_mfma_f32_16x16x32_bf16(a_gy, b_gy, gy, 0,0,0);
    }
    gxs[ct] = gx; gys[ct] = gy;
  }
  __syncthreads();   // all MFMA LDS reads done before overwriting with g

  float An = Atab[d*16 + n];

  // ---- tail (barrier-free, per-wave stripe) ----
  #pragma unroll
  for(int ct=0; ct<4; ct++){
    #pragma unroll
    for(int r=0;r<4;r++)
      gL[(r0 + lk*4 + r)*GST + ct*16 + lr] = gxs[ct][r];
  }
  v4f ab[4];
  #pragma unroll
  for(int j=0;j<4;j++){
    int q = r0*16 + j*64 + l;          // own-wave rows
    int row = q>>4, c4 = (q&15)<<2;
    v4f dv = ((const v4f*)dp)[q];
    #pragma unroll
    for(int r=0;r<4;r++) ab[j][r] = __expf(dv[r]*An);
    v4f gx = *(const v4f*)&gL[row*GST + c4];
    v4f mx = ((const v4f*)mxp)[q];
    ((v4f*)(so + PL))[q] = ab[j]*(mx - gx);
  }
  #pragma unroll
  for(int ct=0; ct<4; ct++){
    #pragma unroll
    for(int r=0;r<4;r++)
      gL[(r0 + lk*4 + r)*GST + ct*16 + lr] = gys[ct][r];
  }
  #pragma unroll
  for(int j=0;j<4;j++){
    int q = r0*16 + j*64 + l;
    int row = q>>4, c4 = (q&15)<<2;
    v4f gy = *(const v4f*)&gL[row*GST + c4];
    v4f my = ((const v4f*)myp)[q];
    ((v4f*)(so + 2*PL))[q] = ab[j]*(my - gy);
  }
}

extern "C" void kernel_launch(void* const* d_in, const int* in_sizes, int n_in,
                              void* d_out, int out_size, void* d_ws, size_t ws_size,
                              hipStream_t stream){
  const float* u_t    = (const float*)d_in[0];
  const float* s_prev = (const float*)d_in[1];
  const float* gamma  = (const float*)d_in[2];
  const float* beta   = (const float*)d_in[3];
  const float* w_d    = (const float*)d_in[4];
  const float* b_d    = (const float*)d_in[5];
  const float* w_B    = (const float*)d_in[6];
  const float* w_C    = (const float*)d_in[7];
  const float* logA   = (const float*)d_in[8];
  const float* Dp     = (const float*)d_in[9];
  const float* dtp    = (const float*)d_in[10];

  char* ws = (char*)d_ws;
  unsigned short* D2w  = (unsigned short*)(ws + OFF_D2);
  float* Atab          = (float*)(ws + OFF_ATAB);
  unsigned short* W9   = (unsigned short*)(ws + OFF_W9);
  unsigned short* unT  = (unsigned short*)(ws + OFF_UNT);
  float* deltaw        = (float*)(ws + OFF_DELTA);
  float* Bvalw         = (float*)(ws + OFF_BVAL);
  float* Cvalw         = (float*)(ws + OFF_CVAL);
  float* part          = (float*)(ws + OFF_PART);

  float* out_y = (float*)d_out;
  float* out_s = out_y + 1048576;

  k_prep  <<<1068, 256, 0, stream>>>(logA, w_d, w_B, w_C, u_t, D2w, Atab, W9, part);
  k_unT   <<<256, 512, 0, stream>>>(u_t, part, gamma, beta, unT);
  k_conv  <<<1536, 256, 0, stream>>>(unT, W9, b_d, dtp, deltaw, Bvalw, Cvalw);
  k_state <<<5120, 256, 0, stream>>>(u_t, s_prev, D2w, Atab, deltaw, Bvalw, Cvalw, Dp, out_y, out_s);
}